// Round 3
// baseline (2244.621 us; speedup 1.0000x reference)
//
#include <hip/hip_runtime.h>
#include <hip/hip_bf16.h>
#include <stdint.h>

typedef __attribute__((ext_vector_type(4))) float f32x4;
typedef __attribute__((ext_vector_type(8))) short bf16x8;
typedef __attribute__((ext_vector_type(8))) unsigned short u16x8;

__device__ __forceinline__ unsigned short f2bf(float f) {
  unsigned int u = __float_as_uint(f);
  u += 0x7fffu + ((u >> 16) & 1u);   // round-to-nearest-even
  return (unsigned short)(u >> 16);
}

__global__ __launch_bounds__(256) void cvt_kernel(const float* __restrict__ in,
                                                  unsigned short* __restrict__ out, int n4) {
  int stride = gridDim.x * blockDim.x;
  for (int i = blockIdx.x * blockDim.x + threadIdx.x; i < n4; i += stride) {
    float4 v = reinterpret_cast<const float4*>(in)[i];
    ushort4 o;
    o.x = f2bf(v.x); o.y = f2bf(v.y); o.z = f2bf(v.z); o.w = f2bf(v.w);
    reinterpret_cast<ushort4*>(out)[i] = o;
  }
}

// C = A[M,Kd] * Bt[N,Kd]^T ; bf16 inputs, f32 accumulate.
// EPI 0: bf16 store row-major [M,N]
// EPI 1: V-transpose bf16 store: dst[(b*1024 + n)*2048 + (m&2047)], b = m>>11
// EPI 2: f32 store row-major with +bias[n]  (final output)
template <int EPI>
__global__ __launch_bounds__(256) void gemm_bt(const unsigned short* __restrict__ A,
                                               const unsigned short* __restrict__ Bt,
                                               unsigned short* __restrict__ C,
                                               float* __restrict__ Cf,
                                               const float* __restrict__ bias,
                                               int M, int N, int Kd) {
  __shared__ unsigned short As[128 * 64];
  __shared__ unsigned short Bs[128 * 64];
  const int tid = threadIdx.x;
  const int lane = tid & 63;
  const int wid = tid >> 6;
  const int wm = wid >> 1, wn = wid & 1;
  const int lc = lane & 15, qr = lane >> 4;
  const int m0 = blockIdx.x * 128, n0 = blockIdx.y * 128;

  f32x4 acc[4][4];
#pragma unroll
  for (int i = 0; i < 4; i++)
#pragma unroll
    for (int j = 0; j < 4; j++) acc[i][j] = (f32x4)0.0f;

  for (int k0 = 0; k0 < Kd; k0 += 64) {
#pragma unroll
    for (int i = 0; i < 4; i++) {
      int c = i * 256 + tid;          // 0..1023 chunk id
      int row = c >> 3;               // 0..127
      int col = (c & 7) << 3;         // 0..56
      *reinterpret_cast<u16x8*>(&As[row * 64 + col]) =
          *reinterpret_cast<const u16x8*>(&A[(size_t)(m0 + row) * Kd + k0 + col]);
      *reinterpret_cast<u16x8*>(&Bs[row * 64 + col]) =
          *reinterpret_cast<const u16x8*>(&Bt[(size_t)(n0 + row) * Kd + k0 + col]);
    }
    __syncthreads();
#pragma unroll
    for (int kk = 0; kk < 2; kk++) {
      bf16x8 a[4], b[4];
#pragma unroll
      for (int mf = 0; mf < 4; mf++)
        a[mf] = *reinterpret_cast<const bf16x8*>(&As[(wm * 64 + mf * 16 + lc) * 64 + kk * 32 + qr * 8]);
#pragma unroll
      for (int nf = 0; nf < 4; nf++)
        b[nf] = *reinterpret_cast<const bf16x8*>(&Bs[(wn * 64 + nf * 16 + lc) * 64 + kk * 32 + qr * 8]);
#pragma unroll
      for (int mf = 0; mf < 4; mf++)
#pragma unroll
        for (int nf = 0; nf < 4; nf++)
          acc[mf][nf] = __builtin_amdgcn_mfma_f32_16x16x32_bf16(a[mf], b[nf], acc[mf][nf], 0, 0, 0);
    }
    __syncthreads();
  }

#pragma unroll
  for (int mf = 0; mf < 4; mf++) {
#pragma unroll
    for (int nf = 0; nf < 4; nf++) {
      const int row0 = m0 + wm * 64 + mf * 16 + qr * 4;
      const int col = n0 + wn * 64 + nf * 16 + lc;
#pragma unroll
      for (int r = 0; r < 4; r++) {
        float v = acc[mf][nf][r];
        int row = row0 + r;
        if (EPI == 0) {
          C[(size_t)row * N + col] = f2bf(v);
        } else if (EPI == 1) {
          int bb = row >> 11, s2 = row & 2047;
          C[((size_t)(bb * 1024 + col)) * 2048 + s2] = f2bf(v);
        } else {
          Cf[(size_t)row * N + col] = v + bias[col];
        }
      }
    }
  }
}

// Flash-style cross attention, register-software-pipelined.
// Flat grid 1024 blocks; XCD-swizzled decode so each XCD owns 4 heads (K/V L2-resident).
// 256 threads = 4 independent waves x 16 q-rows; no __syncthreads in the loop.
__global__ __launch_bounds__(256, 3) void flash_kernel(const unsigned short* __restrict__ Qg,
                                                       const unsigned short* __restrict__ Kg,
                                                       const unsigned short* __restrict__ Vt,
                                                       const float* __restrict__ Wm,
                                                       const int* __restrict__ mask,
                                                       unsigned short* __restrict__ Og) {
  __shared__ unsigned short P_lds[4][16][72];   // per-wave P transpose buffer
  const int tid = threadIdx.x;
  const int lane = tid & 63;
  const int wid = tid >> 6;
  const int lc = lane & 15, qr = lane >> 4;

  // XCD swizzle: consecutive-launch blocks round-robin XCDs; regroup so
  // XCD x gets a contiguous nid chunk => 4 heads per XCD, K/V fits 4MB L2.
  const int bx = blockIdx.x;
  const int nid = (bx & 7) * 128 + (bx >> 3);
  const int b = nid >> 9, h = (nid >> 5) & 15, qt = nid & 31;
  const int q0 = qt * 64 + wid * 16;

  // Q fragments (A-operand): row = lane&15, k = (lane>>4)*8 + kk*32
  bf16x8 aq[2];
#pragma unroll
  for (int kk = 0; kk < 2; kk++)
    aq[kk] = *reinterpret_cast<const bf16x8*>(
        &Qg[(size_t)(b * 2048 + q0 + lc) * 1024 + h * 64 + kk * 32 + qr * 8]);

  int msk[4];
#pragma unroll
  for (int r = 0; r < 4; r++) msk[r] = mask[b * 2048 + q0 + qr * 4 + r];

  float m_run[4], l_run[4];
  f32x4 o_acc[4];
#pragma unroll
  for (int r = 0; r < 4; r++) { m_run[r] = -INFINITY; l_run[r] = 0.f; }
#pragma unroll
  for (int vf = 0; vf < 4; vf++) o_acc[vf] = (f32x4)0.0f;

  const unsigned short* Kb = Kg + (size_t)(b * 2048) * 1024 + h * 64;
  const unsigned short* Vb = Vt + (size_t)(b * 1024 + h * 64) * 2048;
  const float* wbase = Wm + (size_t)(b * 16 + h) * 2048 * 2048 + (size_t)(q0 + qr * 4) * 2048 + lc;

  // Pipeline register buffers (static indexing only — rule #20)
  bf16x8 kf[8];      // K fragments for current tile
  bf16x8 vr[8];      // V fragments for current tile
  float wA[16], wB[16];

  auto loadK = [&](int s0) {
#pragma unroll
    for (int nf = 0; nf < 4; nf++)
#pragma unroll
      for (int kk = 0; kk < 2; kk++)
        kf[nf * 2 + kk] = *reinterpret_cast<const bf16x8*>(
            &Kb[(size_t)(s0 + nf * 16 + lc) * 1024 + kk * 32 + qr * 8]);
  };
  auto loadV = [&](int s0) {
#pragma unroll
    for (int vf = 0; vf < 4; vf++)
#pragma unroll
      for (int kk = 0; kk < 2; kk++)
        vr[vf * 2 + kk] = *reinterpret_cast<const bf16x8*>(
            &Vb[(size_t)(vf * 16 + lc) * 2048 + s0 + kk * 32 + qr * 8]);
  };
  auto loadW = [&](int s0, float (&w)[16]) {
#pragma unroll
    for (int nf = 0; nf < 4; nf++)
#pragma unroll
      for (int r = 0; r < 4; r++)
        w[nf * 4 + r] = wbase[(size_t)r * 2048 + s0 + nf * 16];
  };

  auto tile = [&](int t, float (&wcur)[16], float (&wnxt)[16]) {
    const int s0 = t * 64;
    const bool pre = (t + 1 < 32);
    if (pre) loadW(s0 + 64, wnxt);            // W(t+1): full-tile latency coverage

    // S = Q K^T : col s = lane&15 (+16*nf), row q = (lane>>4)*4+r
    f32x4 sacc[4];
#pragma unroll
    for (int nf = 0; nf < 4; nf++) sacc[nf] = (f32x4)0.0f;
#pragma unroll
    for (int nf = 0; nf < 4; nf++)
#pragma unroll
      for (int kk = 0; kk < 2; kk++)
        sacc[nf] = __builtin_amdgcn_mfma_f32_16x16x32_bf16(aq[kk], kf[nf * 2 + kk], sacc[nf], 0, 0, 0);
    if (pre) loadK(s0 + 64);                  // K(t+1): covered by softmax+PV(t)

    float lg[4][4], tmax[4];
#pragma unroll
    for (int r = 0; r < 4; r++) tmax[r] = -INFINITY;
#pragma unroll
    for (int nf = 0; nf < 4; nf++) {
#pragma unroll
      for (int r = 0; r < 4; r++) {
        float v = msk[r] ? sacc[nf][r] * 0.125f : -INFINITY;
        v *= wcur[nf * 4 + r];
        lg[nf][r] = v;
        tmax[r] = fmaxf(tmax[r], v);
      }
    }
#pragma unroll
    for (int d = 1; d < 16; d <<= 1)
#pragma unroll
      for (int r = 0; r < 4; r++) tmax[r] = fmaxf(tmax[r], __shfl_xor(tmax[r], d));

    float scale[4], rsum[4];
#pragma unroll
    for (int r = 0; r < 4; r++) {
      float mn = fmaxf(m_run[r], tmax[r]);
      scale[r] = __expf(m_run[r] - mn);       // first iter: exp(-inf) = 0
      m_run[r] = mn;
      rsum[r] = 0.f;
    }
#pragma unroll
    for (int nf = 0; nf < 4; nf++) {
#pragma unroll
      for (int r = 0; r < 4; r++) {
        float p = __expf(lg[nf][r] - m_run[r]);
        rsum[r] += p;
        P_lds[wid][qr * 4 + r][nf * 16 + lc] = f2bf(p);
      }
    }
#pragma unroll
    for (int d = 1; d < 16; d <<= 1)
#pragma unroll
      for (int r = 0; r < 4; r++) rsum[r] += __shfl_xor(rsum[r], d);
#pragma unroll
    for (int r = 0; r < 4; r++) l_run[r] = l_run[r] * scale[r] + rsum[r];
#pragma unroll
    for (int vf = 0; vf < 4; vf++)
#pragma unroll
      for (int r = 0; r < 4; r++) o_acc[vf][r] *= scale[r];

    // O += P * V
#pragma unroll
    for (int kk = 0; kk < 2; kk++) {
      bf16x8 pa = *reinterpret_cast<const bf16x8*>(&P_lds[wid][lc][kk * 32 + qr * 8]);
#pragma unroll
      for (int vf = 0; vf < 4; vf++)
        o_acc[vf] = __builtin_amdgcn_mfma_f32_16x16x32_bf16(pa, vr[vf * 2 + kk], o_acc[vf], 0, 0, 0);
    }
    if (pre) loadV(s0 + 64);                  // V(t+1): covered by QK+softmax(t+1)
  };

  loadK(0);
  loadV(0);
  loadW(0, wA);
  for (int t = 0; t < 32; t += 2) {
    tile(t, wA, wB);
    tile(t + 1, wB, wA);
  }

#pragma unroll
  for (int vf = 0; vf < 4; vf++)
#pragma unroll
    for (int r = 0; r < 4; r++) {
      float v = o_acc[vf][r] / l_run[r];
      Og[(size_t)(b * 2048 + q0 + qr * 4 + r) * 1024 + h * 64 + vf * 16 + lc] = f2bf(v);
    }
}

extern "C" void kernel_launch(void* const* d_in, const int* in_sizes, int n_in,
                              void* d_out, int out_size, void* d_ws, size_t ws_size,
                              hipStream_t stream) {
  (void)in_sizes; (void)n_in; (void)out_size; (void)ws_size;
  const float* x1 = (const float*)d_in[0];
  const float* x2 = (const float*)d_in[1];
  const float* Wm = (const float*)d_in[2];
  const int* mask = (const int*)d_in[3];
  const float* Wq = (const float*)d_in[4];
  const float* Wk = (const float*)d_in[5];
  const float* Wv = (const float*)d_in[6];
  const float* Wo = (const float*)d_in[7];
  const float* bo = (const float*)d_in[8];

  char* ws = (char*)d_ws;
  const size_t SZ_X = (size_t)4096 * 1024 * 2;   // 8 MB bf16 activation
  const size_t SZ_W = (size_t)1024 * 1024 * 2;   // 2 MB bf16 weight
  unsigned short* x1b = (unsigned short*)(ws + 0);
  unsigned short* x2b = (unsigned short*)(ws + SZ_X);
  unsigned short* Wqb = (unsigned short*)(ws + 2 * SZ_X);
  unsigned short* Wkb = (unsigned short*)(ws + 2 * SZ_X + SZ_W);
  unsigned short* Wvb = (unsigned short*)(ws + 2 * SZ_X + 2 * SZ_W);
  unsigned short* Wob = (unsigned short*)(ws + 2 * SZ_X + 3 * SZ_W);
  unsigned short* Qb  = (unsigned short*)(ws + 2 * SZ_X + 4 * SZ_W);
  unsigned short* Kb  = (unsigned short*)(ws + 3 * SZ_X + 4 * SZ_W);
  unsigned short* Vtb = (unsigned short*)(ws + 4 * SZ_X + 4 * SZ_W);
  unsigned short* Ob  = (unsigned short*)(ws + 5 * SZ_X + 4 * SZ_W);

  cvt_kernel<<<2048, 256, 0, stream>>>(x1, x1b, 4096 * 1024 / 4);
  cvt_kernel<<<2048, 256, 0, stream>>>(x2, x2b, 4096 * 1024 / 4);
  cvt_kernel<<<512, 256, 0, stream>>>(Wq, Wqb, 1024 * 1024 / 4);
  cvt_kernel<<<512, 256, 0, stream>>>(Wk, Wkb, 1024 * 1024 / 4);
  cvt_kernel<<<512, 256, 0, stream>>>(Wv, Wvb, 1024 * 1024 / 4);
  cvt_kernel<<<512, 256, 0, stream>>>(Wo, Wob, 1024 * 1024 / 4);

  dim3 gg(32, 8);
  gemm_bt<0><<<gg, 256, 0, stream>>>(x1b, Wqb, Qb, nullptr, nullptr, 4096, 1024, 1024);
  gemm_bt<0><<<gg, 256, 0, stream>>>(x2b, Wkb, Kb, nullptr, nullptr, 4096, 1024, 1024);
  gemm_bt<1><<<gg, 256, 0, stream>>>(x2b, Wvb, Vtb, nullptr, nullptr, 4096, 1024, 1024);

  flash_kernel<<<1024, 256, 0, stream>>>(Qb, Kb, Vtb, Wm, mask, Ob);

  gemm_bt<2><<<gg, 256, 0, stream>>>(Ob, Wob, nullptr, (float*)d_out, bo, 4096, 1024, 1024);
}

// Round 4
// 383.485 us; speedup vs baseline: 5.8532x; 5.8532x over previous
//
#include <hip/hip_runtime.h>
#include <hip/hip_bf16.h>
#include <stdint.h>

typedef __attribute__((ext_vector_type(4))) float f32x4;
typedef __attribute__((ext_vector_type(8))) short bf16x8;
typedef __attribute__((ext_vector_type(8))) unsigned short u16x8;

__device__ __forceinline__ unsigned short f2bf(float f) {
  unsigned int u = __float_as_uint(f);
  u += 0x7fffu + ((u >> 16) & 1u);   // round-to-nearest-even
  return (unsigned short)(u >> 16);
}

__global__ __launch_bounds__(256) void cvt_kernel(const float* __restrict__ in,
                                                  unsigned short* __restrict__ out, int n4) {
  int stride = gridDim.x * blockDim.x;
  for (int i = blockIdx.x * blockDim.x + threadIdx.x; i < n4; i += stride) {
    float4 v = reinterpret_cast<const float4*>(in)[i];
    ushort4 o;
    o.x = f2bf(v.x); o.y = f2bf(v.y); o.z = f2bf(v.z); o.w = f2bf(v.w);
    reinterpret_cast<ushort4*>(out)[i] = o;
  }
}

// C = A[M,Kd] * Bt[N,Kd]^T ; bf16 inputs, f32 accumulate.
// EPI 0: bf16 store row-major [M,N]
// EPI 1: V-transpose bf16 store: dst[(b*1024 + n)*2048 + (m&2047)], b = m>>11
// EPI 2: f32 store row-major with +bias[n]  (final output)
template <int EPI>
__global__ __launch_bounds__(256) void gemm_bt(const unsigned short* __restrict__ A,
                                               const unsigned short* __restrict__ Bt,
                                               unsigned short* __restrict__ C,
                                               float* __restrict__ Cf,
                                               const float* __restrict__ bias,
                                               int M, int N, int Kd) {
  __shared__ unsigned short As[128 * 64];
  __shared__ unsigned short Bs[128 * 64];
  const int tid = threadIdx.x;
  const int lane = tid & 63;
  const int wid = tid >> 6;
  const int wm = wid >> 1, wn = wid & 1;
  const int lc = lane & 15, qr = lane >> 4;
  const int m0 = blockIdx.x * 128, n0 = blockIdx.y * 128;

  f32x4 acc[4][4];
#pragma unroll
  for (int i = 0; i < 4; i++)
#pragma unroll
    for (int j = 0; j < 4; j++) acc[i][j] = (f32x4)0.0f;

  for (int k0 = 0; k0 < Kd; k0 += 64) {
#pragma unroll
    for (int i = 0; i < 4; i++) {
      int c = i * 256 + tid;          // 0..1023 chunk id
      int row = c >> 3;               // 0..127
      int col = (c & 7) << 3;         // 0..56
      *reinterpret_cast<u16x8*>(&As[row * 64 + col]) =
          *reinterpret_cast<const u16x8*>(&A[(size_t)(m0 + row) * Kd + k0 + col]);
      *reinterpret_cast<u16x8*>(&Bs[row * 64 + col]) =
          *reinterpret_cast<const u16x8*>(&Bt[(size_t)(n0 + row) * Kd + k0 + col]);
    }
    __syncthreads();
#pragma unroll
    for (int kk = 0; kk < 2; kk++) {
      bf16x8 a[4], b[4];
#pragma unroll
      for (int mf = 0; mf < 4; mf++)
        a[mf] = *reinterpret_cast<const bf16x8*>(&As[(wm * 64 + mf * 16 + lc) * 64 + kk * 32 + qr * 8]);
#pragma unroll
      for (int nf = 0; nf < 4; nf++)
        b[nf] = *reinterpret_cast<const bf16x8*>(&Bs[(wn * 64 + nf * 16 + lc) * 64 + kk * 32 + qr * 8]);
#pragma unroll
      for (int mf = 0; mf < 4; mf++)
#pragma unroll
        for (int nf = 0; nf < 4; nf++)
          acc[mf][nf] = __builtin_amdgcn_mfma_f32_16x16x32_bf16(a[mf], b[nf], acc[mf][nf], 0, 0, 0);
    }
    __syncthreads();
  }

#pragma unroll
  for (int mf = 0; mf < 4; mf++) {
#pragma unroll
    for (int nf = 0; nf < 4; nf++) {
      const int row0 = m0 + wm * 64 + mf * 16 + qr * 4;
      const int col = n0 + wn * 64 + nf * 16 + lc;
#pragma unroll
      for (int r = 0; r < 4; r++) {
        float v = acc[mf][nf][r];
        int row = row0 + r;
        if (EPI == 0) {
          C[(size_t)row * N + col] = f2bf(v);
        } else if (EPI == 1) {
          int bb = row >> 11, s2 = row & 2047;
          C[((size_t)(bb * 1024 + col)) * 2048 + s2] = f2bf(v);
        } else {
          Cf[(size_t)row * N + col] = v + bias[col];
        }
      }
    }
  }
}

// Flash-style cross attention, register-software-pipelined.
// Flat grid 1024 blocks; XCD-swizzled decode so each XCD owns 4 heads (K/V L2-resident).
// 256 threads = 4 independent waves x 16 q-rows; no __syncthreads in the loop.
// All pipeline buffers are plain local arrays indexed ONLY by compile-time
// constants inside macros (no lambdas / array refs — those demoted them to
// scratch in the previous round: VGPR 84 + 4.3 GB scratch writes).
__global__ __launch_bounds__(256, 2) void flash_kernel(const unsigned short* __restrict__ Qg,
                                                       const unsigned short* __restrict__ Kg,
                                                       const unsigned short* __restrict__ Vt,
                                                       const float* __restrict__ Wm,
                                                       const int* __restrict__ mask,
                                                       unsigned short* __restrict__ Og) {
  __shared__ unsigned short P_lds[4][16][72];   // per-wave P transpose buffer
  const int tid = threadIdx.x;
  const int lane = tid & 63;
  const int wid = tid >> 6;
  const int lc = lane & 15, qr = lane >> 4;

  const int bx = blockIdx.x;
  const int nid = (bx & 7) * 128 + (bx >> 3);
  const int b = nid >> 9, h = (nid >> 5) & 15, qt = nid & 31;
  const int q0 = qt * 64 + wid * 16;

  // Q fragments (A-operand): row = lane&15, k = (lane>>4)*8 + kk*32
  bf16x8 aq[2];
#pragma unroll
  for (int kk = 0; kk < 2; kk++)
    aq[kk] = *reinterpret_cast<const bf16x8*>(
        &Qg[(size_t)(b * 2048 + q0 + lc) * 1024 + h * 64 + kk * 32 + qr * 8]);

  int msk[4];
#pragma unroll
  for (int r = 0; r < 4; r++) msk[r] = mask[b * 2048 + q0 + qr * 4 + r];

  float m_run[4], l_run[4];
  f32x4 o_acc[4];
#pragma unroll
  for (int r = 0; r < 4; r++) { m_run[r] = -INFINITY; l_run[r] = 0.f; }
#pragma unroll
  for (int vf = 0; vf < 4; vf++) o_acc[vf] = (f32x4)0.0f;

  const unsigned short* Kb = Kg + (size_t)(b * 2048) * 1024 + h * 64;
  const unsigned short* Vb = Vt + (size_t)(b * 1024 + h * 64) * 2048;
  const float* wbase = Wm + (size_t)(b * 16 + h) * 2048 * 2048 + (size_t)(q0 + qr * 4) * 2048 + lc;

  bf16x8 kf[8];        // K fragments (single buffer: reloaded right after last use)
  bf16x8 vr[8];        // V fragments (single buffer: reloaded right after last use)
  float wA[16], wB[16];  // W double buffer (consumed mid-tile, loaded a tile ahead)

#define LOADK(S0)                                                           \
  _Pragma("unroll") for (int nf = 0; nf < 4; nf++)                          \
  _Pragma("unroll") for (int kk = 0; kk < 2; kk++)                          \
      kf[nf * 2 + kk] = *reinterpret_cast<const bf16x8*>(                   \
          &Kb[(size_t)((S0) + nf * 16 + lc) * 1024 + kk * 32 + qr * 8]);

#define LOADV(S0)                                                           \
  _Pragma("unroll") for (int vf = 0; vf < 4; vf++)                          \
  _Pragma("unroll") for (int kk = 0; kk < 2; kk++)                          \
      vr[vf * 2 + kk] = *reinterpret_cast<const bf16x8*>(                   \
          &Vb[(size_t)(vf * 16 + lc) * 2048 + (S0) + kk * 32 + qr * 8]);

#define LOADW(S0, W)                                                        \
  _Pragma("unroll") for (int nf = 0; nf < 4; nf++)                          \
  _Pragma("unroll") for (int r = 0; r < 4; r++)                             \
      W[nf * 4 + r] = wbase[(size_t)r * 2048 + (S0) + nf * 16];

#define TILEBODY(T, WCUR, WNXT)                                             \
  {                                                                         \
    const int s0 = (T) * 64;                                                \
    if ((T) < 31) { LOADW(s0 + 64, WNXT); }                                 \
    f32x4 sacc[4];                                                          \
    _Pragma("unroll") for (int nf = 0; nf < 4; nf++) sacc[nf] = (f32x4)0.0f;\
    _Pragma("unroll") for (int nf = 0; nf < 4; nf++)                        \
    _Pragma("unroll") for (int kk = 0; kk < 2; kk++)                        \
        sacc[nf] = __builtin_amdgcn_mfma_f32_16x16x32_bf16(                 \
            aq[kk], kf[nf * 2 + kk], sacc[nf], 0, 0, 0);                    \
    if ((T) < 31) { LOADK(s0 + 64); }                                       \
    float lg[4][4], tmax[4];                                                \
    _Pragma("unroll") for (int r = 0; r < 4; r++) tmax[r] = -INFINITY;      \
    _Pragma("unroll") for (int nf = 0; nf < 4; nf++)                        \
    _Pragma("unroll") for (int r = 0; r < 4; r++) {                         \
      float v = msk[r] ? sacc[nf][r] * 0.125f : -INFINITY;                  \
      v *= WCUR[nf * 4 + r];                                                \
      lg[nf][r] = v;                                                        \
      tmax[r] = fmaxf(tmax[r], v);                                          \
    }                                                                       \
    _Pragma("unroll") for (int d = 1; d < 16; d <<= 1)                      \
    _Pragma("unroll") for (int r = 0; r < 4; r++)                           \
        tmax[r] = fmaxf(tmax[r], __shfl_xor(tmax[r], d));                   \
    float scale[4], rsum[4];                                                \
    _Pragma("unroll") for (int r = 0; r < 4; r++) {                         \
      float mn = fmaxf(m_run[r], tmax[r]);                                  \
      scale[r] = __expf(m_run[r] - mn);                                     \
      m_run[r] = mn;                                                        \
      rsum[r] = 0.f;                                                        \
    }                                                                       \
    _Pragma("unroll") for (int nf = 0; nf < 4; nf++)                        \
    _Pragma("unroll") for (int r = 0; r < 4; r++) {                         \
      float p = __expf(lg[nf][r] - m_run[r]);                               \
      rsum[r] += p;                                                         \
      P_lds[wid][qr * 4 + r][nf * 16 + lc] = f2bf(p);                       \
    }                                                                       \
    _Pragma("unroll") for (int d = 1; d < 16; d <<= 1)                      \
    _Pragma("unroll") for (int r = 0; r < 4; r++)                           \
        rsum[r] += __shfl_xor(rsum[r], d);                                  \
    _Pragma("unroll") for (int r = 0; r < 4; r++)                           \
        l_run[r] = l_run[r] * scale[r] + rsum[r];                           \
    _Pragma("unroll") for (int vf = 0; vf < 4; vf++)                        \
    _Pragma("unroll") for (int r = 0; r < 4; r++) o_acc[vf][r] *= scale[r]; \
    _Pragma("unroll") for (int kk = 0; kk < 2; kk++) {                      \
      bf16x8 pa = *reinterpret_cast<const bf16x8*>(                         \
          &P_lds[wid][lc][kk * 32 + qr * 8]);                               \
      _Pragma("unroll") for (int vf = 0; vf < 4; vf++)                      \
          o_acc[vf] = __builtin_amdgcn_mfma_f32_16x16x32_bf16(              \
              pa, vr[vf * 2 + kk], o_acc[vf], 0, 0, 0);                     \
    }                                                                       \
    if ((T) < 31) { LOADV(s0 + 64); }                                       \
  }

  LOADK(0);
  LOADV(0);
  LOADW(0, wA);
#pragma unroll 1
  for (int t = 0; t < 32; t += 2) {
    TILEBODY(t, wA, wB);
    TILEBODY(t + 1, wB, wA);
  }

#pragma unroll
  for (int vf = 0; vf < 4; vf++)
#pragma unroll
    for (int r = 0; r < 4; r++) {
      float v = o_acc[vf][r] / l_run[r];
      Og[(size_t)(b * 2048 + q0 + qr * 4 + r) * 1024 + h * 64 + vf * 16 + lc] = f2bf(v);
    }
}

extern "C" void kernel_launch(void* const* d_in, const int* in_sizes, int n_in,
                              void* d_out, int out_size, void* d_ws, size_t ws_size,
                              hipStream_t stream) {
  (void)in_sizes; (void)n_in; (void)out_size; (void)ws_size;
  const float* x1 = (const float*)d_in[0];
  const float* x2 = (const float*)d_in[1];
  const float* Wm = (const float*)d_in[2];
  const int* mask = (const int*)d_in[3];
  const float* Wq = (const float*)d_in[4];
  const float* Wk = (const float*)d_in[5];
  const float* Wv = (const float*)d_in[6];
  const float* Wo = (const float*)d_in[7];
  const float* bo = (const float*)d_in[8];

  char* ws = (char*)d_ws;
  const size_t SZ_X = (size_t)4096 * 1024 * 2;   // 8 MB bf16 activation
  const size_t SZ_W = (size_t)1024 * 1024 * 2;   // 2 MB bf16 weight
  unsigned short* x1b = (unsigned short*)(ws + 0);
  unsigned short* x2b = (unsigned short*)(ws + SZ_X);
  unsigned short* Wqb = (unsigned short*)(ws + 2 * SZ_X);
  unsigned short* Wkb = (unsigned short*)(ws + 2 * SZ_X + SZ_W);
  unsigned short* Wvb = (unsigned short*)(ws + 2 * SZ_X + 2 * SZ_W);
  unsigned short* Wob = (unsigned short*)(ws + 2 * SZ_X + 3 * SZ_W);
  unsigned short* Qb  = (unsigned short*)(ws + 2 * SZ_X + 4 * SZ_W);
  unsigned short* Kb  = (unsigned short*)(ws + 3 * SZ_X + 4 * SZ_W);
  unsigned short* Vtb = (unsigned short*)(ws + 4 * SZ_X + 4 * SZ_W);
  unsigned short* Ob  = (unsigned short*)(ws + 5 * SZ_X + 4 * SZ_W);

  cvt_kernel<<<2048, 256, 0, stream>>>(x1, x1b, 4096 * 1024 / 4);
  cvt_kernel<<<2048, 256, 0, stream>>>(x2, x2b, 4096 * 1024 / 4);
  cvt_kernel<<<512, 256, 0, stream>>>(Wq, Wqb, 1024 * 1024 / 4);
  cvt_kernel<<<512, 256, 0, stream>>>(Wk, Wkb, 1024 * 1024 / 4);
  cvt_kernel<<<512, 256, 0, stream>>>(Wv, Wvb, 1024 * 1024 / 4);
  cvt_kernel<<<512, 256, 0, stream>>>(Wo, Wob, 1024 * 1024 / 4);

  dim3 gg(32, 8);
  gemm_bt<0><<<gg, 256, 0, stream>>>(x1b, Wqb, Qb, nullptr, nullptr, 4096, 1024, 1024);
  gemm_bt<0><<<gg, 256, 0, stream>>>(x2b, Wkb, Kb, nullptr, nullptr, 4096, 1024, 1024);
  gemm_bt<1><<<gg, 256, 0, stream>>>(x2b, Wvb, Vtb, nullptr, nullptr, 4096, 1024, 1024);

  flash_kernel<<<1024, 256, 0, stream>>>(Qb, Kb, Vtb, Wm, mask, Ob);

  gemm_bt<2><<<gg, 256, 0, stream>>>(Ob, Wob, nullptr, (float*)d_out, bo, 4096, 1024, 1024);
}